// Round 12
// baseline (413.343 us; speedup 1.0000x reference)
//
#include <hip/hip_runtime.h>
#include <math.h>

#define NA 10000
#define NE 150000
#define NRBF 20
#define CUT 5.0f
#define EPSV 1e-8f
#define NBATCH 64
#define CAP 48
#define PI_F 3.14159265358979323846f

typedef short bf16x8 __attribute__((ext_vector_type(8)));
typedef float f32x4 __attribute__((ext_vector_type(4)));
typedef __fp16 h16x2 __attribute__((ext_vector_type(2)));
typedef unsigned short u16;

__device__ __forceinline__ u16 f2b(float x) {
    unsigned u = __builtin_bit_cast(unsigned, x);
    return (u16)((u + 0x7FFFu + ((u >> 16) & 1u)) >> 16);
}
__device__ __forceinline__ float b2f(u16 b) {
    unsigned u = ((unsigned)b) << 16;
    return __builtin_bit_cast(float, u);
}
__device__ __forceinline__ float silu_f(float x) { return x / (1.0f + expf(-x)); }

// packed-weight offsets (in u16 elements)
#define P_IC1 0
#define P_IC2 49152
#define P_MIX 196608
#define P_C1  294912
#define P_C2  393216
#define P_O1  540672
#define P_O2  557056
#define P_FWH 573440            // fW as f16 pairs: [10][1152] u32 = 23040 u16 slots *2
#define P_TOT 619520

// ---- pack weights -> MFMA B-frag bf16; fW -> f16 pairs; init q (folded) ----
__global__ __launch_bounds__(64) void pack_k(
    const float* __restrict__ ic1W, const float* __restrict__ ic2W,
    const float* __restrict__ mixW, const float* __restrict__ c1W,
    const float* __restrict__ c2W, const float* __restrict__ o1W,
    const float* __restrict__ o2W, const float* __restrict__ fW,
    const float* __restrict__ emb, const int* __restrict__ zn,
    float* __restrict__ q, u16* __restrict__ packs) {
    int id = blockIdx.x;
    if (id >= 1138) {   // init q: blocks 1138..6137, float4 per thread
        int elem = ((id - 1138) * 64 + (int)threadIdx.x) * 4;   // < 1.28M
        int a = elem >> 7, c = elem & 127;
        *(float4*)(q + elem) = *(const float4*)(emb + (size_t)zn[a] * 128 + c);
        return;
    }
    if (id >= 1120) {   // fW f16-pair pack, blocks 1120..1137
        int col = (id - 1120) * 64 + (int)threadIdx.x;   // < 1152
        unsigned* dst32 = (unsigned*)(packs + P_FWH);
        #pragma unroll
        for (int p = 0; p < 10; p++) {
            h16x2 v = __builtin_amdgcn_cvt_pkrtz(fW[(size_t)(2 * p) * 1152 + col],
                                                 fW[(size_t)(2 * p + 1) * 1152 + col]);
            dst32[p * 1152 + col] = __builtin_bit_cast(unsigned, v);
        }
        return;
    }
    const float* src; u16* dst; int N, rel;
    if (id < 96)        { int m = id / 32;          rel = id % 32; src = ic1W + m * 16384; dst = packs + P_IC1 + m * 16384; N = 128; }
    else if (id < 384)  { id -= 96;  int m = id / 96; rel = id % 96; src = ic2W + m * 49152; dst = packs + P_IC2 + m * 49152; N = 384; }
    else if (id < 576)  { id -= 384; int m = id / 64; rel = id % 64; src = mixW + m * 32768; dst = packs + P_MIX + m * 32768; N = 256; }
    else if (id < 768)  { id -= 576; int m = id / 64; rel = id % 64; src = c1W  + m * 32768; dst = packs + P_C1  + m * 32768; N = 128; }
    else if (id < 1056) { id -= 768; int m = id / 96; rel = id % 96; src = c2W  + m * 49152; dst = packs + P_C2  + m * 49152; N = 384; }
    else if (id < 1088) { rel = id - 1056; src = o1W; dst = packs + P_O1; N = 128; }
    else                { rel = id - 1088; src = o2W; dst = packs + P_O2; N = 128; }
    int NBT = N >> 4;
    int kb = rel / NBT, nb = rel % NBT;
    int l = threadIdx.x;
    int col = nb * 16 + (l & 15);
    int k0 = kb * 32 + 8 * (l >> 4);
    u16 v[8];
    #pragma unroll
    for (int i = 0; i < 8; i++) v[i] = f2b(src[(size_t)(k0 + i) * N + col]);
    *(bf16x8*)(dst + rel * 512 + l * 8) = *(bf16x8*)v;
}

// stage MT x K f32 rows -> LDS bf16 [MT][K+8]
template<int MT, int K>
__device__ __forceinline__ void stageA(const float* __restrict__ src, int row0,
                                       int maxrow, u16* As) {
    const int NV = MT * K / 4;
    for (int idx = threadIdx.x; idx < NV; idx += 256) {
        int r = idx / (K / 4), c4 = idx % (K / 4);
        float4 v = make_float4(0.f, 0.f, 0.f, 0.f);
        if (row0 + r < maxrow) v = *(const float4*)(src + (size_t)(row0 + r) * K + c4 * 4);
        uint2 o;
        o.x = (unsigned)f2b(v.x) | ((unsigned)f2b(v.y) << 16);
        o.y = (unsigned)f2b(v.z) | ((unsigned)f2b(v.w) << 16);
        *(uint2*)(As + r * (K + 8) + c4 * 4) = o;
    }
}

__device__ __forceinline__ bf16x8 aFrag(const u16* As, int stride, int row, int k0) {
    return *(const bf16x8*)(As + row * stride + k0);
}
__device__ __forceinline__ bf16x8 bFrag(const u16* __restrict__ pack, int NBT,
                                        int ks, int nb, int l) {
    return *(const bf16x8*)(pack + ((size_t)(ks * NBT + nb) * 64 + l) * 8);
}
#define MFMA(a, b, c) __builtin_amdgcn_mfma_f32_16x16x32_bf16(a, b, c, 0, 0, 0)

// ---- edge geometry + phi(f16 pairs) written in bucket-slot order ----
__global__ void edge_geom_k(const float* __restrict__ pos,
                            const int* __restrict__ idx_i, const int* __restrict__ idx_j,
                            float* __restrict__ edata, int* __restrict__ cnt,
                            int* __restrict__ bucketj) {
    int e = blockIdx.x * blockDim.x + threadIdx.x;
    if (e >= NE) return;
    int i = idx_i[e], j = idx_j[e];
    float rx = pos[j * 3 + 0] - pos[i * 3 + 0];
    float ry = pos[j * 3 + 1] - pos[i * 3 + 1];
    float rz = pos[j * 3 + 2] - pos[i * 3 + 2];
    float d = sqrtf(rx * rx + ry * ry + rz * rz);
    float inv = 1.0f / d;
    float fc = (d < CUT) ? 0.5f * (cosf(d * PI_F / CUT) + 1.0f) : 0.0f;
    const float width = CUT / (float)(NRBF - 1);
    const float coeff = -0.5f / (width * width);
    float ph[NRBF];
    #pragma unroll
    for (int k = 0; k < NRBF; k++) {
        float t = d - (float)k * width;
        ph[k] = expf(coeff * t * t);
    }
    int slot = atomicAdd(&cnt[i], 1);
    if (slot < CAP) {
        bucketj[i * CAP + slot] = j;
        float* ed = edata + ((size_t)i * CAP + slot) * 16;
        ed[0] = rx * inv; ed[1] = ry * inv; ed[2] = rz * inv; ed[3] = fc;
        h16x2* php = (h16x2*)(ed + 4);
        #pragma unroll
        for (int p = 0; p < 10; p++)
            php[p] = __builtin_amdgcn_cvt_pkrtz(ph[2 * p], ph[2 * p + 1]);
    }
}

// ---- pad bucket to multiple of 4; dummy slots: zeroed edata -> zero contribution ----
__global__ void pad_k(int* __restrict__ cnt, int* __restrict__ bucketj,
                      float* __restrict__ edata) {
    int a = blockIdx.x * blockDim.x + threadIdx.x;
    if (a >= NA) return;
    int n = cnt[a]; if (n > CAP) n = CAP;
    int n4 = (n + 3) & ~3;
    for (int k = n; k < n4; k++) {
        bucketj[a * CAP + k] = 0;
        float* ed = edata + ((size_t)a * CAP + k) * 16;
        #pragma unroll
        for (int t = 0; t < 16; t++) ed[t] = 0.f;
    }
    cnt[a] = n4;
}

// ---- x_atom = silu(q@W1+b1)@W2+b2 -> x_bf (coalesced u16 stores) ----
__global__ __launch_bounds__(256) void mlp1_k(
    const float* __restrict__ q, const u16* __restrict__ pW1, const float* __restrict__ b1,
    const u16* __restrict__ pW2, const float* __restrict__ b2, u16* __restrict__ x_bf) {
    __shared__ u16 As[32 * 136];
    __shared__ u16 Hs[32 * 136];
    int abase = blockIdx.x * 32;
    stageA<32, 128>(q, abase, NA, As);
    __syncthreads();
    int l = threadIdx.x & 63, w = threadIdx.x >> 6, lm = l & 15, lg = l >> 4;
    f32x4 acc[2][2];
    #pragma unroll
    for (int j = 0; j < 2; j++)
        #pragma unroll
        for (int mi = 0; mi < 2; mi++) acc[j][mi] = (f32x4){0.f, 0.f, 0.f, 0.f};
    #pragma unroll
    for (int ks = 0; ks < 4; ks++) {
        bf16x8 a0 = aFrag(As, 136, lm, ks * 32 + 8 * lg);
        bf16x8 a1 = aFrag(As, 136, 16 + lm, ks * 32 + 8 * lg);
        #pragma unroll
        for (int j = 0; j < 2; j++) {
            bf16x8 b = bFrag(pW1, 8, ks, w + 4 * j, l);
            acc[j][0] = MFMA(a0, b, acc[j][0]);
            acc[j][1] = MFMA(a1, b, acc[j][1]);
        }
    }
    #pragma unroll
    for (int j = 0; j < 2; j++) {
        int col = 16 * (w + 4 * j) + lm;
        float bb = b1[col];
        #pragma unroll
        for (int mi = 0; mi < 2; mi++)
            #pragma unroll
            for (int v = 0; v < 4; v++)
                Hs[(16 * mi + 4 * lg + v) * 136 + col] = f2b(silu_f(acc[j][mi][v] + bb));
    }
    __syncthreads();
    f32x4 acc2[6][2];
    #pragma unroll
    for (int j = 0; j < 6; j++)
        #pragma unroll
        for (int mi = 0; mi < 2; mi++) acc2[j][mi] = (f32x4){0.f, 0.f, 0.f, 0.f};
    #pragma unroll
    for (int ks = 0; ks < 4; ks++) {
        bf16x8 a0 = aFrag(Hs, 136, lm, ks * 32 + 8 * lg);
        bf16x8 a1 = aFrag(Hs, 136, 16 + lm, ks * 32 + 8 * lg);
        #pragma unroll
        for (int j = 0; j < 6; j++) {
            bf16x8 b = bFrag(pW2, 24, ks, w + 4 * j, l);
            acc2[j][0] = MFMA(a0, b, acc2[j][0]);
            acc2[j][1] = MFMA(a1, b, acc2[j][1]);
        }
    }
    #pragma unroll
    for (int j = 0; j < 6; j++) {
        int col = 16 * (w + 4 * j) + lm;
        float bb = b2[col];
        #pragma unroll
        for (int mi = 0; mi < 2; mi++)
            #pragma unroll
            for (int v = 0; v < 4; v++) {
                int ga = abase + 16 * mi + 4 * lg + v;
                if (ga < NA) x_bf[(size_t)ga * 384 + col] = f2b(acc2[j][mi][v] + bb);
            }
    }
}

// ---- per-atom edge reduction; prepacked f16 fW + int4 bucket groups ----
template<int IT0>
__global__ __launch_bounds__(128) void gather_k(
    const unsigned* __restrict__ fWh, const float* __restrict__ fb,
    const u16* __restrict__ x_bf, const u16* __restrict__ mu_bf,
    const float* __restrict__ edata, const int* __restrict__ cnt,
    const int* __restrict__ bucketj, int it,
    float* __restrict__ q, float* __restrict__ muF) {
    int a = blockIdx.x;
    int c = threadIdx.x;
    int cb = it * 384;
    h16x2 wp0[10], wp1[10], wp2[10];
    #pragma unroll
    for (int p = 0; p < 10; p++) {
        wp0[p] = __builtin_bit_cast(h16x2, fWh[p * 1152 + cb + c]);
        wp1[p] = __builtin_bit_cast(h16x2, fWh[p * 1152 + cb + 128 + c]);
        if (!IT0) wp2[p] = __builtin_bit_cast(h16x2, fWh[p * 1152 + cb + 256 + c]);
    }
    float fb0 = fb[cb + c], fb1 = fb[cb + 128 + c];
    float fb2 = IT0 ? 0.f : fb[cb + 256 + c];
    int n4 = cnt[a];  // padded to multiple of 4
    const int* bj = bucketj + a * CAP;
    const float* eb = edata + (size_t)a * CAP * 16;
    float adq = 0.f, am0 = 0.f, am1 = 0.f, am2 = 0.f;
    for (int e0 = 0; e0 < n4; e0 += 4) {
        int4 j4 = *(const int4*)(bj + e0);
        #pragma unroll
        for (int u = 0; u < 4; u++) {
            int j = __builtin_amdgcn_readfirstlane(
                u == 0 ? j4.x : u == 1 ? j4.y : u == 2 ? j4.z : j4.w);
            const float* ed = eb + (size_t)(e0 + u) * 16;
            const u16* xr = x_bf + (size_t)j * 384;
            float xc0 = b2f(xr[c]), xc1 = b2f(xr[128 + c]);
            float xc2 = 0.f, m0 = 0.f, m1 = 0.f, m2 = 0.f;
            if (!IT0) {
                xc2 = b2f(xr[256 + c]);
                const u16* mr = mu_bf + (size_t)j * 384;
                m0 = b2f(mr[c]); m1 = b2f(mr[128 + c]); m2 = b2f(mr[256 + c]);
            }
            float4 gg = *(const float4*)ed;
            const h16x2* php = (const h16x2*)(ed + 4);
            float f0 = fb0, f1 = fb1, f2 = fb2;
            #pragma unroll
            for (int p = 0; p < 10; p++) {
                h16x2 ph = php[p];
                f0 = __builtin_amdgcn_fdot2(ph, wp0[p], f0, false);
                f1 = __builtin_amdgcn_fdot2(ph, wp1[p], f1, false);
                if (!IT0) f2 = __builtin_amdgcn_fdot2(ph, wp2[p], f2, false);
            }
            f0 *= gg.w; f1 *= gg.w;
            float x0 = f0 * xc0, x1 = f1 * xc1;
            adq += x0;
            am0 += x1 * gg.x;
            am1 += x1 * gg.y;
            am2 += x1 * gg.z;
            if (!IT0) {
                f2 *= gg.w;
                float x2 = f2 * xc2;
                am0 += x2 * m0; am1 += x2 * m1; am2 += x2 * m2;
            }
        }
    }
    q[(size_t)a * 128 + c] += adq;
    muF[(size_t)a * 384 + c] += am0;
    muF[(size_t)a * 384 + 128 + c] += am1;
    muF[(size_t)a * 384 + 256 + c] += am2;
}

// ---- fused: mu_mix (MFMA) + norm + ctx MLP (MFMA) + final q/mu update ----
__global__ __launch_bounds__(256) void mixctx_k(
    float* __restrict__ q, float* __restrict__ muF, u16* __restrict__ mu_bf,
    const u16* __restrict__ pM,
    const u16* __restrict__ pC1, const float* __restrict__ c1b,
    const u16* __restrict__ pC2, const float* __restrict__ c2b) {
    __shared__ u16 As[48 * 136];
    __shared__ u16 mmL[16 * 768];
    __shared__ u16 Cs[16 * 264];
    __shared__ u16 Hs[16 * 136];
    int abase = blockIdx.x * 16;
    stageA<48, 128>(muF, abase * 3, 3 * NA, As);
    __syncthreads();
    int l = threadIdx.x & 63, w = threadIdx.x >> 6, lm = l & 15, lg = l >> 4;
    {   // mix: A 48x128, B 128x256
        f32x4 acc[4][3];
        #pragma unroll
        for (int j = 0; j < 4; j++)
            #pragma unroll
            for (int mi = 0; mi < 3; mi++) acc[j][mi] = (f32x4){0.f, 0.f, 0.f, 0.f};
        #pragma unroll
        for (int ks = 0; ks < 4; ks++) {
            bf16x8 a[3];
            #pragma unroll
            for (int mi = 0; mi < 3; mi++) a[mi] = aFrag(As, 136, 16 * mi + lm, ks * 32 + 8 * lg);
            #pragma unroll
            for (int j = 0; j < 4; j++) {
                bf16x8 b = bFrag(pM, 16, ks, w + 4 * j, l);
                #pragma unroll
                for (int mi = 0; mi < 3; mi++) acc[j][mi] = MFMA(a[mi], b, acc[j][mi]);
            }
        }
        #pragma unroll
        for (int j = 0; j < 4; j++) {
            int col = 16 * (w + 4 * j) + lm;
            #pragma unroll
            for (int mi = 0; mi < 3; mi++)
                #pragma unroll
                for (int v = 0; v < 4; v++) {
                    int R = 16 * mi + 4 * lg + v;
                    mmL[(R / 3) * 768 + (R % 3) * 256 + col] = f2b(acc[j][mi][v]);
                }
        }
    }
    __syncthreads();
    for (int idx = threadIdx.x; idx < 16 * 128; idx += 256) {
        int a = idx >> 7, cc = idx & 127;
        int ga = abase + a;
        float s = EPSV;
        #pragma unroll
        for (int d = 0; d < 3; d++) {
            float t = b2f(mmL[a * 768 + d * 256 + cc]);
            s += t * t;
        }
        float qv = (ga < NA) ? q[(size_t)ga * 128 + cc] : 0.f;
        Cs[a * 264 + cc] = f2b(qv);
        Cs[a * 264 + 128 + cc] = f2b(sqrtf(s));
    }
    __syncthreads();
    {   // ctx1: A 16x256, B 256x128
        f32x4 h[2];
        h[0] = (f32x4){0.f, 0.f, 0.f, 0.f}; h[1] = (f32x4){0.f, 0.f, 0.f, 0.f};
        #pragma unroll
        for (int ks = 0; ks < 8; ks++) {
            bf16x8 a0 = aFrag(Cs, 264, lm, ks * 32 + 8 * lg);
            #pragma unroll
            for (int j = 0; j < 2; j++) {
                bf16x8 b = bFrag(pC1, 8, ks, w + 4 * j, l);
                h[j] = MFMA(a0, b, h[j]);
            }
        }
        #pragma unroll
        for (int j = 0; j < 2; j++) {
            int col = 16 * (w + 4 * j) + lm;
            float bb = c1b[col];
            #pragma unroll
            for (int v = 0; v < 4; v++)
                Hs[(4 * lg + v) * 136 + col] = f2b(silu_f(h[j][v] + bb));
        }
    }
    __syncthreads();
    f32x4 acc2[6];
    #pragma unroll
    for (int j = 0; j < 6; j++) acc2[j] = (f32x4){0.f, 0.f, 0.f, 0.f};
    #pragma unroll
    for (int ks = 0; ks < 4; ks++) {
        bf16x8 a0 = aFrag(Hs, 136, lm, ks * 32 + 8 * lg);
        #pragma unroll
        for (int j = 0; j < 6; j++) {
            bf16x8 b = bFrag(pC2, 24, ks, w + 4 * j, l);
            acc2[j] = MFMA(a0, b, acc2[j]);
        }
    }
    #pragma unroll
    for (int j = 0; j < 6; j++) {
        float bb = c2b[16 * (w + 4 * j) + lm];
        #pragma unroll
        for (int v = 0; v < 4; v++) acc2[j][v] += bb;
    }
    #pragma unroll
    for (int v = 0; v < 4; v++) {
        int al = 4 * lg + v;
        int ga = abase + al;
        if (ga >= NA) continue;
        #pragma unroll
        for (int jj = 0; jj < 2; jj++) {
            int cc = 16 * w + 64 * jj + lm;
            float x0 = acc2[jj][v], x1 = acc2[jj + 2][v], x2 = acc2[jj + 4][v];
            float dot = 0.f, muW[3];
            #pragma unroll
            for (int d = 0; d < 3; d++) {
                float muV = b2f(mmL[al * 768 + d * 256 + cc]);
                muW[d] = b2f(mmL[al * 768 + d * 256 + 128 + cc]);
                dot += muV * muW[d];
            }
            q[(size_t)ga * 128 + cc] += x0 + x2 * dot;
            #pragma unroll
            for (int d = 0; d < 3; d++) {
                size_t mo = (size_t)ga * 384 + d * 128 + cc;
                float m = muF[mo] + x1 * muW[d];
                muF[mo] = m;
                mu_bf[mo] = f2b(m);
            }
        }
    }
}

// ---- readout: silu(silu(q@o1)@o2)@o3 + per-block LDS segment-sum ----
__global__ __launch_bounds__(256) void readout_k(
    const float* __restrict__ q, const u16* __restrict__ pO1, const float* __restrict__ o1b,
    const u16* __restrict__ pO2, const float* __restrict__ o2b,
    const float* __restrict__ o3W, const float* __restrict__ o3b,
    const int* __restrict__ idx_m, float* __restrict__ y) {
    __shared__ u16 As[32 * 136];
    __shared__ u16 Hs[32 * 136];
    __shared__ float red[256];
    __shared__ float part[NBATCH];
    __shared__ int mlo, mhi;
    int abase = blockIdx.x * 32;
    stageA<32, 128>(q, abase, NA, As);
    __syncthreads();
    int l = threadIdx.x & 63, w = threadIdx.x >> 6, lm = l & 15, lg = l >> 4;
    f32x4 acc[2][2];
    #pragma unroll
    for (int j = 0; j < 2; j++)
        #pragma unroll
        for (int mi = 0; mi < 2; mi++) acc[j][mi] = (f32x4){0.f, 0.f, 0.f, 0.f};
    #pragma unroll
    for (int ks = 0; ks < 4; ks++) {
        bf16x8 a0 = aFrag(As, 136, lm, ks * 32 + 8 * lg);
        bf16x8 a1 = aFrag(As, 136, 16 + lm, ks * 32 + 8 * lg);
        #pragma unroll
        for (int j = 0; j < 2; j++) {
            bf16x8 b = bFrag(pO1, 8, ks, w + 4 * j, l);
            acc[j][0] = MFMA(a0, b, acc[j][0]);
            acc[j][1] = MFMA(a1, b, acc[j][1]);
        }
    }
    #pragma unroll
    for (int j = 0; j < 2; j++) {
        int col = 16 * (w + 4 * j) + lm;
        float bb = o1b[col];
        #pragma unroll
        for (int mi = 0; mi < 2; mi++)
            #pragma unroll
            for (int v = 0; v < 4; v++)
                Hs[(16 * mi + 4 * lg + v) * 136 + col] = f2b(silu_f(acc[j][mi][v] + bb));
    }
    __syncthreads();
    f32x4 acc2[2][2];
    #pragma unroll
    for (int j = 0; j < 2; j++)
        #pragma unroll
        for (int mi = 0; mi < 2; mi++) acc2[j][mi] = (f32x4){0.f, 0.f, 0.f, 0.f};
    #pragma unroll
    for (int ks = 0; ks < 4; ks++) {
        bf16x8 a0 = aFrag(Hs, 136, lm, ks * 32 + 8 * lg);
        bf16x8 a1 = aFrag(Hs, 136, 16 + lm, ks * 32 + 8 * lg);
        #pragma unroll
        for (int j = 0; j < 2; j++) {
            bf16x8 b = bFrag(pO2, 8, ks, w + 4 * j, l);
            acc2[j][0] = MFMA(a0, b, acc2[j][0]);
            acc2[j][1] = MFMA(a1, b, acc2[j][1]);
        }
    }
    #pragma unroll
    for (int j = 0; j < 2; j++) {
        int col = 16 * (w + 4 * j) + lm;
        float bb = o2b[col];
        #pragma unroll
        for (int mi = 0; mi < 2; mi++)
            #pragma unroll
            for (int v = 0; v < 4; v++)
                As[(16 * mi + 4 * lg + v) * 136 + col] = f2b(silu_f(acc2[j][mi][v] + bb));
    }
    if (threadIdx.x < NBATCH) part[threadIdx.x] = 0.f;
    if (threadIdx.x == 0) { mlo = NBATCH; mhi = -1; }
    __syncthreads();
    int a = threadIdx.x >> 3, gseg = threadIdx.x & 7;
    float p = 0.f;
    #pragma unroll
    for (int cc = 0; cc < 16; cc++) {
        int c = gseg * 16 + cc;
        p += b2f(As[a * 136 + c]) * o3W[c];
    }
    red[threadIdx.x] = p;
    __syncthreads();
    if (gseg == 0) {
        float s = 0.f;
        #pragma unroll
        for (int k = 0; k < 8; k++) s += red[a * 8 + k];
        int ga = abase + a;
        if (ga < NA) {
            int m = idx_m[ga];
            atomicAdd(&part[m], s + o3b[0]);
            atomicMin(&mlo, m);
            atomicMax(&mhi, m);
        }
    }
    __syncthreads();
    for (int m = mlo + (int)threadIdx.x; m <= mhi; m += 256)
        atomicAdd(&y[m], part[m]);
}

extern "C" void kernel_launch(void* const* d_in, const int* in_sizes, int n_in,
                              void* d_out, int out_size, void* d_ws, size_t ws_size,
                              hipStream_t stream) {
    const float* pos  = (const float*)d_in[0];
    const float* emb  = (const float*)d_in[1];
    const float* fW   = (const float*)d_in[2];
    const float* fb   = (const float*)d_in[3];
    const float* ic1W = (const float*)d_in[4];
    const float* ic1b = (const float*)d_in[5];
    const float* ic2W = (const float*)d_in[6];
    const float* ic2b = (const float*)d_in[7];
    const float* mixW = (const float*)d_in[8];
    const float* c1W  = (const float*)d_in[9];
    const float* c1b  = (const float*)d_in[10];
    const float* c2W  = (const float*)d_in[11];
    const float* c2b  = (const float*)d_in[12];
    const float* o1W  = (const float*)d_in[13];
    const float* o1b  = (const float*)d_in[14];
    const float* o2W  = (const float*)d_in[15];
    const float* o2b  = (const float*)d_in[16];
    const float* o3W  = (const float*)d_in[17];
    const float* o3b  = (const float*)d_in[18];
    const int* zn     = (const int*)d_in[19];
    const int* idx_i  = (const int*)d_in[20];
    const int* idx_j  = (const int*)d_in[21];
    const int* idx_m  = (const int*)d_in[22];

    float* y   = (float*)d_out;
    float* muF = (float*)d_out + NBATCH;  // (NA,3,128) f32 master

    char* wp = (char*)d_ws;
    float* q      = (float*)wp;  wp += (size_t)NA * 128 * 4;       // 5.12 MB
    u16*   x_bf   = (u16*)wp;    wp += (size_t)NA * 384 * 2;       // 7.68 MB
    u16*   mu_bf  = (u16*)wp;    wp += (size_t)NA * 384 * 2;       // 7.68 MB
    float* edata  = (float*)wp;  wp += (size_t)NA * CAP * 16 * 4;  // 30.72 MB
    int*   cnt    = (int*)wp;    wp += (size_t)NA * 4;
    int*   bucketj= (int*)wp;    wp += (size_t)NA * CAP * 4;       // 1.92 MB
    u16*   packs  = (u16*)wp;    wp += (size_t)P_TOT * 2;          // 1.24 MB

    hipMemsetAsync(d_out, 0, (size_t)(NBATCH + (size_t)NA * 384) * 4, stream);
    hipMemsetAsync(cnt, 0, (size_t)NA * 4, stream);

    pack_k<<<6138, 64, 0, stream>>>(ic1W, ic2W, mixW, c1W, c2W, o1W, o2W, fW,
                                    emb, zn, q, packs);
    edge_geom_k<<<(NE + 255) / 256, 256, 0, stream>>>(pos, idx_i, idx_j, edata, cnt, bucketj);
    pad_k<<<(NA + 255) / 256, 256, 0, stream>>>(cnt, bucketj, edata);

    const unsigned* fWh = (const unsigned*)(packs + P_FWH);

    for (int it = 0; it < 3; it++) {
        mlp1_k<<<313, 256, 0, stream>>>(
            q, packs + P_IC1 + it * 16384, ic1b + it * 128,
            packs + P_IC2 + it * 49152, ic2b + it * 384, x_bf);
        if (it == 0)
            gather_k<1><<<NA, 128, 0, stream>>>(
                fWh, fb, x_bf, mu_bf, edata, cnt, bucketj, it, q, muF);
        else
            gather_k<0><<<NA, 128, 0, stream>>>(
                fWh, fb, x_bf, mu_bf, edata, cnt, bucketj, it, q, muF);
        mixctx_k<<<(NA + 15) / 16, 256, 0, stream>>>(
            q, muF, mu_bf,
            packs + P_MIX + it * 32768,
            packs + P_C1 + it * 32768, c1b + it * 128,
            packs + P_C2 + it * 49152, c2b + it * 384);
    }

    readout_k<<<313, 256, 0, stream>>>(q, packs + P_O1, o1b, packs + P_O2, o2b,
                                       o3W, o3b, idx_m, y);
}

// Round 13
// 379.984 us; speedup vs baseline: 1.0878x; 1.0878x over previous
//
#include <hip/hip_runtime.h>
#include <math.h>

#define NA 10000
#define NE 150000
#define NRBF 20
#define CUT 5.0f
#define EPSV 1e-8f
#define NBATCH 64
#define CAP 48
#define PI_F 3.14159265358979323846f

typedef short bf16x8 __attribute__((ext_vector_type(8)));
typedef float f32x4 __attribute__((ext_vector_type(4)));
typedef __fp16 h16x2 __attribute__((ext_vector_type(2)));
typedef unsigned short u16;

__device__ __forceinline__ u16 f2b(float x) {
    unsigned u = __builtin_bit_cast(unsigned, x);
    return (u16)((u + 0x7FFFu + ((u >> 16) & 1u)) >> 16);
}
__device__ __forceinline__ float b2f(u16 b) {
    unsigned u = ((unsigned)b) << 16;
    return __builtin_bit_cast(float, u);
}
__device__ __forceinline__ float silu_f(float x) { return x / (1.0f + expf(-x)); }

// packed-weight offsets (in u16 elements)
#define P_IC1 0
#define P_IC2 49152
#define P_MIX 196608
#define P_C1  294912
#define P_C2  393216
#define P_O1  540672
#define P_O2  557056
#define P_FWH 573440            // fW as f16 pairs: [10][1152] u32
#define P_TOT 619520

// ---- pack weights -> MFMA B-frag bf16; fW -> f16 pairs; init q (folded) ----
__global__ __launch_bounds__(64) void pack_k(
    const float* __restrict__ ic1W, const float* __restrict__ ic2W,
    const float* __restrict__ mixW, const float* __restrict__ c1W,
    const float* __restrict__ c2W, const float* __restrict__ o1W,
    const float* __restrict__ o2W, const float* __restrict__ fW,
    const float* __restrict__ emb, const int* __restrict__ zn,
    float* __restrict__ q, u16* __restrict__ packs) {
    int id = blockIdx.x;
    if (id >= 1138) {   // init q: blocks 1138..6137, float4 per thread
        int elem = ((id - 1138) * 64 + (int)threadIdx.x) * 4;
        int a = elem >> 7, c = elem & 127;
        *(float4*)(q + elem) = *(const float4*)(emb + (size_t)zn[a] * 128 + c);
        return;
    }
    if (id >= 1120) {   // fW f16-pair pack
        int col = (id - 1120) * 64 + (int)threadIdx.x;
        unsigned* dst32 = (unsigned*)(packs + P_FWH);
        #pragma unroll
        for (int p = 0; p < 10; p++) {
            h16x2 v = __builtin_amdgcn_cvt_pkrtz(fW[(size_t)(2 * p) * 1152 + col],
                                                 fW[(size_t)(2 * p + 1) * 1152 + col]);
            dst32[p * 1152 + col] = __builtin_bit_cast(unsigned, v);
        }
        return;
    }
    const float* src; u16* dst; int N, rel;
    if (id < 96)        { int m = id / 32;          rel = id % 32; src = ic1W + m * 16384; dst = packs + P_IC1 + m * 16384; N = 128; }
    else if (id < 384)  { id -= 96;  int m = id / 96; rel = id % 96; src = ic2W + m * 49152; dst = packs + P_IC2 + m * 49152; N = 384; }
    else if (id < 576)  { id -= 384; int m = id / 64; rel = id % 64; src = mixW + m * 32768; dst = packs + P_MIX + m * 32768; N = 256; }
    else if (id < 768)  { id -= 576; int m = id / 64; rel = id % 64; src = c1W  + m * 32768; dst = packs + P_C1  + m * 32768; N = 128; }
    else if (id < 1056) { id -= 768; int m = id / 96; rel = id % 96; src = c2W  + m * 49152; dst = packs + P_C2  + m * 49152; N = 384; }
    else if (id < 1088) { rel = id - 1056; src = o1W; dst = packs + P_O1; N = 128; }
    else                { rel = id - 1088; src = o2W; dst = packs + P_O2; N = 128; }
    int NBT = N >> 4;
    int kb = rel / NBT, nb = rel % NBT;
    int l = threadIdx.x;
    int col = nb * 16 + (l & 15);
    int k0 = kb * 32 + 8 * (l >> 4);
    u16 v[8];
    #pragma unroll
    for (int i = 0; i < 8; i++) v[i] = f2b(src[(size_t)(k0 + i) * N + col]);
    *(bf16x8*)(dst + rel * 512 + l * 8) = *(bf16x8*)v;
}

// stage MT x K f32 rows -> LDS bf16 [MT][K+8]
template<int MT, int K>
__device__ __forceinline__ void stageA(const float* __restrict__ src, int row0,
                                       int maxrow, u16* As) {
    const int NV = MT * K / 4;
    for (int idx = threadIdx.x; idx < NV; idx += 256) {
        int r = idx / (K / 4), c4 = idx % (K / 4);
        float4 v = make_float4(0.f, 0.f, 0.f, 0.f);
        if (row0 + r < maxrow) v = *(const float4*)(src + (size_t)(row0 + r) * K + c4 * 4);
        uint2 o;
        o.x = (unsigned)f2b(v.x) | ((unsigned)f2b(v.y) << 16);
        o.y = (unsigned)f2b(v.z) | ((unsigned)f2b(v.w) << 16);
        *(uint2*)(As + r * (K + 8) + c4 * 4) = o;
    }
}

__device__ __forceinline__ bf16x8 aFrag(const u16* As, int stride, int row, int k0) {
    return *(const bf16x8*)(As + row * stride + k0);
}
__device__ __forceinline__ bf16x8 bFrag(const u16* __restrict__ pack, int NBT,
                                        int ks, int nb, int l) {
    return *(const bf16x8*)(pack + ((size_t)(ks * NBT + nb) * 64 + l) * 8);
}
#define MFMA(a, b, c) __builtin_amdgcn_mfma_f32_16x16x32_bf16(a, b, c, 0, 0, 0)

// ---- edge geometry + phi(f16 pairs) written in bucket-slot order ----
__global__ void edge_geom_k(const float* __restrict__ pos,
                            const int* __restrict__ idx_i, const int* __restrict__ idx_j,
                            float* __restrict__ edata, int* __restrict__ cnt,
                            int* __restrict__ bucketj) {
    int e = blockIdx.x * blockDim.x + threadIdx.x;
    if (e >= NE) return;
    int i = idx_i[e], j = idx_j[e];
    float rx = pos[j * 3 + 0] - pos[i * 3 + 0];
    float ry = pos[j * 3 + 1] - pos[i * 3 + 1];
    float rz = pos[j * 3 + 2] - pos[i * 3 + 2];
    float d = sqrtf(rx * rx + ry * ry + rz * rz);
    float inv = 1.0f / d;
    float fc = (d < CUT) ? 0.5f * (cosf(d * PI_F / CUT) + 1.0f) : 0.0f;
    const float width = CUT / (float)(NRBF - 1);
    const float coeff = -0.5f / (width * width);
    float ph[NRBF];
    #pragma unroll
    for (int k = 0; k < NRBF; k++) {
        float t = d - (float)k * width;
        ph[k] = expf(coeff * t * t);
    }
    int slot = atomicAdd(&cnt[i], 1);
    if (slot < CAP) {
        bucketj[i * CAP + slot] = j;
        float* ed = edata + ((size_t)i * CAP + slot) * 16;
        ed[0] = rx * inv; ed[1] = ry * inv; ed[2] = rz * inv; ed[3] = fc;
        h16x2* php = (h16x2*)(ed + 4);
        #pragma unroll
        for (int p = 0; p < 10; p++)
            php[p] = __builtin_amdgcn_cvt_pkrtz(ph[2 * p], ph[2 * p + 1]);
    }
}

// ---- x_atom = silu(q@W1+b1)@W2+b2 -> x_bf ----
__global__ __launch_bounds__(256) void mlp1_k(
    const float* __restrict__ q, const u16* __restrict__ pW1, const float* __restrict__ b1,
    const u16* __restrict__ pW2, const float* __restrict__ b2, u16* __restrict__ x_bf) {
    __shared__ u16 As[32 * 136];
    __shared__ u16 Hs[32 * 136];
    int abase = blockIdx.x * 32;
    stageA<32, 128>(q, abase, NA, As);
    __syncthreads();
    int l = threadIdx.x & 63, w = threadIdx.x >> 6, lm = l & 15, lg = l >> 4;
    f32x4 acc[2][2];
    #pragma unroll
    for (int j = 0; j < 2; j++)
        #pragma unroll
        for (int mi = 0; mi < 2; mi++) acc[j][mi] = (f32x4){0.f, 0.f, 0.f, 0.f};
    #pragma unroll
    for (int ks = 0; ks < 4; ks++) {
        bf16x8 a0 = aFrag(As, 136, lm, ks * 32 + 8 * lg);
        bf16x8 a1 = aFrag(As, 136, 16 + lm, ks * 32 + 8 * lg);
        #pragma unroll
        for (int j = 0; j < 2; j++) {
            bf16x8 b = bFrag(pW1, 8, ks, w + 4 * j, l);
            acc[j][0] = MFMA(a0, b, acc[j][0]);
            acc[j][1] = MFMA(a1, b, acc[j][1]);
        }
    }
    #pragma unroll
    for (int j = 0; j < 2; j++) {
        int col = 16 * (w + 4 * j) + lm;
        float bb = b1[col];
        #pragma unroll
        for (int mi = 0; mi < 2; mi++)
            #pragma unroll
            for (int v = 0; v < 4; v++)
                Hs[(16 * mi + 4 * lg + v) * 136 + col] = f2b(silu_f(acc[j][mi][v] + bb));
    }
    __syncthreads();
    f32x4 acc2[6][2];
    #pragma unroll
    for (int j = 0; j < 6; j++)
        #pragma unroll
        for (int mi = 0; mi < 2; mi++) acc2[j][mi] = (f32x4){0.f, 0.f, 0.f, 0.f};
    #pragma unroll
    for (int ks = 0; ks < 4; ks++) {
        bf16x8 a0 = aFrag(Hs, 136, lm, ks * 32 + 8 * lg);
        bf16x8 a1 = aFrag(Hs, 136, 16 + lm, ks * 32 + 8 * lg);
        #pragma unroll
        for (int j = 0; j < 6; j++) {
            bf16x8 b = bFrag(pW2, 24, ks, w + 4 * j, l);
            acc2[j][0] = MFMA(a0, b, acc2[j][0]);
            acc2[j][1] = MFMA(a1, b, acc2[j][1]);
        }
    }
    #pragma unroll
    for (int j = 0; j < 6; j++) {
        int col = 16 * (w + 4 * j) + lm;
        float bb = b2[col];
        #pragma unroll
        for (int mi = 0; mi < 2; mi++)
            #pragma unroll
            for (int v = 0; v < 4; v++) {
                int ga = abase + 16 * mi + 4 * lg + v;
                if (ga < NA) x_bf[(size_t)ga * 384 + col] = f2b(acc2[j][mi][v] + bb);
            }
    }
}

// ---- per-atom edge reduction; plain serial loop + prepacked f16 fW ----
template<int IT0>
__global__ __launch_bounds__(128) void gather_k(
    const unsigned* __restrict__ fWh, const float* __restrict__ fb,
    const u16* __restrict__ x_bf, const u16* __restrict__ mu_bf,
    const float* __restrict__ edata, const int* __restrict__ cnt,
    const int* __restrict__ bucketj, int it,
    float* __restrict__ q, float* __restrict__ muF) {
    int a = blockIdx.x;
    int c = threadIdx.x;
    int cb = it * 384;
    h16x2 wp0[10], wp1[10], wp2[10];
    #pragma unroll
    for (int p = 0; p < 10; p++) {
        wp0[p] = __builtin_bit_cast(h16x2, fWh[p * 1152 + cb + c]);
        wp1[p] = __builtin_bit_cast(h16x2, fWh[p * 1152 + cb + 128 + c]);
        if (!IT0) wp2[p] = __builtin_bit_cast(h16x2, fWh[p * 1152 + cb + 256 + c]);
    }
    float fb0 = fb[cb + c], fb1 = fb[cb + 128 + c];
    float fb2 = IT0 ? 0.f : fb[cb + 256 + c];
    int n = cnt[a]; if (n > CAP) n = CAP;
    const int* bj = bucketj + a * CAP;
    const float* eb = edata + (size_t)a * CAP * 16;
    float adq = 0.f, am0 = 0.f, am1 = 0.f, am2 = 0.f;
    for (int ei = 0; ei < n; ei++) {
        int j = __builtin_amdgcn_readfirstlane(bj[ei]);
        const float* ed = eb + (size_t)ei * 16;
        float4 gg = *(const float4*)ed;
        const h16x2* php = (const h16x2*)(ed + 4);
        const u16* xr = x_bf + (size_t)j * 384;
        float xc0 = b2f(xr[c]), xc1 = b2f(xr[128 + c]);
        float xc2 = 0.f, m0 = 0.f, m1 = 0.f, m2 = 0.f;
        if (!IT0) {
            xc2 = b2f(xr[256 + c]);
            const u16* mr = mu_bf + (size_t)j * 384;
            m0 = b2f(mr[c]); m1 = b2f(mr[128 + c]); m2 = b2f(mr[256 + c]);
        }
        float f0 = fb0, f1 = fb1, f2 = fb2;
        #pragma unroll
        for (int p = 0; p < 10; p++) {
            h16x2 ph = php[p];
            f0 = __builtin_amdgcn_fdot2(ph, wp0[p], f0, false);
            f1 = __builtin_amdgcn_fdot2(ph, wp1[p], f1, false);
            if (!IT0) f2 = __builtin_amdgcn_fdot2(ph, wp2[p], f2, false);
        }
        f0 *= gg.w; f1 *= gg.w;
        float x0 = f0 * xc0, x1 = f1 * xc1;
        adq += x0;
        am0 += x1 * gg.x;
        am1 += x1 * gg.y;
        am2 += x1 * gg.z;
        if (!IT0) {
            f2 *= gg.w;
            float x2 = f2 * xc2;
            am0 += x2 * m0; am1 += x2 * m1; am2 += x2 * m2;
        }
    }
    q[(size_t)a * 128 + c] += adq;
    muF[(size_t)a * 384 + c] += am0;
    muF[(size_t)a * 384 + 128 + c] += am1;
    muF[(size_t)a * 384 + 256 + c] += am2;
}

// ---- fused: mu_mix (MFMA) + norm + ctx MLP (MFMA) + final q/mu update ----
__global__ __launch_bounds__(256) void mixctx_k(
    float* __restrict__ q, float* __restrict__ muF, u16* __restrict__ mu_bf,
    const u16* __restrict__ pM,
    const u16* __restrict__ pC1, const float* __restrict__ c1b,
    const u16* __restrict__ pC2, const float* __restrict__ c2b) {
    __shared__ u16 As[48 * 136];
    __shared__ u16 mmL[16 * 768];
    __shared__ u16 Cs[16 * 264];
    __shared__ u16 Hs[16 * 136];
    int abase = blockIdx.x * 16;
    stageA<48, 128>(muF, abase * 3, 3 * NA, As);
    __syncthreads();
    int l = threadIdx.x & 63, w = threadIdx.x >> 6, lm = l & 15, lg = l >> 4;
    {   // mix: A 48x128, B 128x256
        f32x4 acc[4][3];
        #pragma unroll
        for (int j = 0; j < 4; j++)
            #pragma unroll
            for (int mi = 0; mi < 3; mi++) acc[j][mi] = (f32x4){0.f, 0.f, 0.f, 0.f};
        #pragma unroll
        for (int ks = 0; ks < 4; ks++) {
            bf16x8 a[3];
            #pragma unroll
            for (int mi = 0; mi < 3; mi++) a[mi] = aFrag(As, 136, 16 * mi + lm, ks * 32 + 8 * lg);
            #pragma unroll
            for (int j = 0; j < 4; j++) {
                bf16x8 b = bFrag(pM, 16, ks, w + 4 * j, l);
                #pragma unroll
                for (int mi = 0; mi < 3; mi++) acc[j][mi] = MFMA(a[mi], b, acc[j][mi]);
            }
        }
        #pragma unroll
        for (int j = 0; j < 4; j++) {
            int col = 16 * (w + 4 * j) + lm;
            #pragma unroll
            for (int mi = 0; mi < 3; mi++)
                #pragma unroll
                for (int v = 0; v < 4; v++) {
                    int R = 16 * mi + 4 * lg + v;
                    mmL[(R / 3) * 768 + (R % 3) * 256 + col] = f2b(acc[j][mi][v]);
                }
        }
    }
    __syncthreads();
    for (int idx = threadIdx.x; idx < 16 * 128; idx += 256) {
        int a = idx >> 7, cc = idx & 127;
        int ga = abase + a;
        float s = EPSV;
        #pragma unroll
        for (int d = 0; d < 3; d++) {
            float t = b2f(mmL[a * 768 + d * 256 + cc]);
            s += t * t;
        }
        float qv = (ga < NA) ? q[(size_t)ga * 128 + cc] : 0.f;
        Cs[a * 264 + cc] = f2b(qv);
        Cs[a * 264 + 128 + cc] = f2b(sqrtf(s));
    }
    __syncthreads();
    {   // ctx1: A 16x256, B 256x128
        f32x4 h[2];
        h[0] = (f32x4){0.f, 0.f, 0.f, 0.f}; h[1] = (f32x4){0.f, 0.f, 0.f, 0.f};
        #pragma unroll
        for (int ks = 0; ks < 8; ks++) {
            bf16x8 a0 = aFrag(Cs, 264, lm, ks * 32 + 8 * lg);
            #pragma unroll
            for (int j = 0; j < 2; j++) {
                bf16x8 b = bFrag(pC1, 8, ks, w + 4 * j, l);
                h[j] = MFMA(a0, b, h[j]);
            }
        }
        #pragma unroll
        for (int j = 0; j < 2; j++) {
            int col = 16 * (w + 4 * j) + lm;
            float bb = c1b[col];
            #pragma unroll
            for (int v = 0; v < 4; v++)
                Hs[(4 * lg + v) * 136 + col] = f2b(silu_f(h[j][v] + bb));
        }
    }
    __syncthreads();
    f32x4 acc2[6];
    #pragma unroll
    for (int j = 0; j < 6; j++) acc2[j] = (f32x4){0.f, 0.f, 0.f, 0.f};
    #pragma unroll
    for (int ks = 0; ks < 4; ks++) {
        bf16x8 a0 = aFrag(Hs, 136, lm, ks * 32 + 8 * lg);
        #pragma unroll
        for (int j = 0; j < 6; j++) {
            bf16x8 b = bFrag(pC2, 24, ks, w + 4 * j, l);
            acc2[j] = MFMA(a0, b, acc2[j]);
        }
    }
    #pragma unroll
    for (int j = 0; j < 6; j++) {
        float bb = c2b[16 * (w + 4 * j) + lm];
        #pragma unroll
        for (int v = 0; v < 4; v++) acc2[j][v] += bb;
    }
    #pragma unroll
    for (int v = 0; v < 4; v++) {
        int al = 4 * lg + v;
        int ga = abase + al;
        if (ga >= NA) continue;
        #pragma unroll
        for (int jj = 0; jj < 2; jj++) {
            int cc = 16 * w + 64 * jj + lm;
            float x0 = acc2[jj][v], x1 = acc2[jj + 2][v], x2 = acc2[jj + 4][v];
            float dot = 0.f, muW[3];
            #pragma unroll
            for (int d = 0; d < 3; d++) {
                float muV = b2f(mmL[al * 768 + d * 256 + cc]);
                muW[d] = b2f(mmL[al * 768 + d * 256 + 128 + cc]);
                dot += muV * muW[d];
            }
            q[(size_t)ga * 128 + cc] += x0 + x2 * dot;
            #pragma unroll
            for (int d = 0; d < 3; d++) {
                size_t mo = (size_t)ga * 384 + d * 128 + cc;
                float m = muF[mo] + x1 * muW[d];
                muF[mo] = m;
                mu_bf[mo] = f2b(m);
            }
        }
    }
}

// ---- readout: silu(silu(q@o1)@o2)@o3 + per-block LDS segment-sum ----
__global__ __launch_bounds__(256) void readout_k(
    const float* __restrict__ q, const u16* __restrict__ pO1, const float* __restrict__ o1b,
    const u16* __restrict__ pO2, const float* __restrict__ o2b,
    const float* __restrict__ o3W, const float* __restrict__ o3b,
    const int* __restrict__ idx_m, float* __restrict__ y) {
    __shared__ u16 As[32 * 136];
    __shared__ u16 Hs[32 * 136];
    __shared__ float red[256];
    __shared__ float part[NBATCH];
    __shared__ int mlo, mhi;
    int abase = blockIdx.x * 32;
    stageA<32, 128>(q, abase, NA, As);
    __syncthreads();
    int l = threadIdx.x & 63, w = threadIdx.x >> 6, lm = l & 15, lg = l >> 4;
    f32x4 acc[2][2];
    #pragma unroll
    for (int j = 0; j < 2; j++)
        #pragma unroll
        for (int mi = 0; mi < 2; mi++) acc[j][mi] = (f32x4){0.f, 0.f, 0.f, 0.f};
    #pragma unroll
    for (int ks = 0; ks < 4; ks++) {
        bf16x8 a0 = aFrag(As, 136, lm, ks * 32 + 8 * lg);
        bf16x8 a1 = aFrag(As, 136, 16 + lm, ks * 32 + 8 * lg);
        #pragma unroll
        for (int j = 0; j < 2; j++) {
            bf16x8 b = bFrag(pO1, 8, ks, w + 4 * j, l);
            acc[j][0] = MFMA(a0, b, acc[j][0]);
            acc[j][1] = MFMA(a1, b, acc[j][1]);
        }
    }
    #pragma unroll
    for (int j = 0; j < 2; j++) {
        int col = 16 * (w + 4 * j) + lm;
        float bb = o1b[col];
        #pragma unroll
        for (int mi = 0; mi < 2; mi++)
            #pragma unroll
            for (int v = 0; v < 4; v++)
                Hs[(16 * mi + 4 * lg + v) * 136 + col] = f2b(silu_f(acc[j][mi][v] + bb));
    }
    __syncthreads();
    f32x4 acc2[2][2];
    #pragma unroll
    for (int j = 0; j < 2; j++)
        #pragma unroll
        for (int mi = 0; mi < 2; mi++) acc2[j][mi] = (f32x4){0.f, 0.f, 0.f, 0.f};
    #pragma unroll
    for (int ks = 0; ks < 4; ks++) {
        bf16x8 a0 = aFrag(Hs, 136, lm, ks * 32 + 8 * lg);
        bf16x8 a1 = aFrag(Hs, 136, 16 + lm, ks * 32 + 8 * lg);
        #pragma unroll
        for (int j = 0; j < 2; j++) {
            bf16x8 b = bFrag(pO2, 8, ks, w + 4 * j, l);
            acc2[j][0] = MFMA(a0, b, acc2[j][0]);
            acc2[j][1] = MFMA(a1, b, acc2[j][1]);
        }
    }
    #pragma unroll
    for (int j = 0; j < 2; j++) {
        int col = 16 * (w + 4 * j) + lm;
        float bb = o2b[col];
        #pragma unroll
        for (int mi = 0; mi < 2; mi++)
            #pragma unroll
            for (int v = 0; v < 4; v++)
                As[(16 * mi + 4 * lg + v) * 136 + col] = f2b(silu_f(acc2[j][mi][v] + bb));
    }
    if (threadIdx.x < NBATCH) part[threadIdx.x] = 0.f;
    if (threadIdx.x == 0) { mlo = NBATCH; mhi = -1; }
    __syncthreads();
    int a = threadIdx.x >> 3, gseg = threadIdx.x & 7;
    float p = 0.f;
    #pragma unroll
    for (int cc = 0; cc < 16; cc++) {
        int c = gseg * 16 + cc;
        p += b2f(As[a * 136 + c]) * o3W[c];
    }
    red[threadIdx.x] = p;
    __syncthreads();
    if (gseg == 0) {
        float s = 0.f;
        #pragma unroll
        for (int k = 0; k < 8; k++) s += red[a * 8 + k];
        int ga = abase + a;
        if (ga < NA) {
            int m = idx_m[ga];
            atomicAdd(&part[m], s + o3b[0]);
            atomicMin(&mlo, m);
            atomicMax(&mhi, m);
        }
    }
    __syncthreads();
    for (int m = mlo + (int)threadIdx.x; m <= mhi; m += 256)
        atomicAdd(&y[m], part[m]);
}

extern "C" void kernel_launch(void* const* d_in, const int* in_sizes, int n_in,
                              void* d_out, int out_size, void* d_ws, size_t ws_size,
                              hipStream_t stream) {
    const float* pos  = (const float*)d_in[0];
    const float* emb  = (const float*)d_in[1];
    const float* fW   = (const float*)d_in[2];
    const float* fb   = (const float*)d_in[3];
    const float* ic1W = (const float*)d_in[4];
    const float* ic1b = (const float*)d_in[5];
    const float* ic2W = (const float*)d_in[6];
    const float* ic2b = (const float*)d_in[7];
    const float* mixW = (const float*)d_in[8];
    const float* c1W  = (const float*)d_in[9];
    const float* c1b  = (const float*)d_in[10];
    const float* c2W  = (const float*)d_in[11];
    const float* c2b  = (const float*)d_in[12];
    const float* o1W  = (const float*)d_in[13];
    const float* o1b  = (const float*)d_in[14];
    const float* o2W  = (const float*)d_in[15];
    const float* o2b  = (const float*)d_in[16];
    const float* o3W  = (const float*)d_in[17];
    const float* o3b  = (const float*)d_in[18];
    const int* zn     = (const int*)d_in[19];
    const int* idx_i  = (const int*)d_in[20];
    const int* idx_j  = (const int*)d_in[21];
    const int* idx_m  = (const int*)d_in[22];

    float* y   = (float*)d_out;
    float* muF = (float*)d_out + NBATCH;  // (NA,3,128) f32 master

    char* wp = (char*)d_ws;
    float* q      = (float*)wp;  wp += (size_t)NA * 128 * 4;
    u16*   x_bf   = (u16*)wp;    wp += (size_t)NA * 384 * 2;
    u16*   mu_bf  = (u16*)wp;    wp += (size_t)NA * 384 * 2;
    float* edata  = (float*)wp;  wp += (size_t)NA * CAP * 16 * 4;
    int*   cnt    = (int*)wp;    wp += (size_t)NA * 4;
    int*   bucketj= (int*)wp;    wp += (size_t)NA * CAP * 4;
    u16*   packs  = (u16*)wp;    wp += (size_t)P_TOT * 2;

    hipMemsetAsync(d_out, 0, (size_t)(NBATCH + (size_t)NA * 384) * 4, stream);
    hipMemsetAsync(cnt, 0, (size_t)NA * 4, stream);

    pack_k<<<6138, 64, 0, stream>>>(ic1W, ic2W, mixW, c1W, c2W, o1W, o2W, fW,
                                    emb, zn, q, packs);
    edge_geom_k<<<(NE + 255) / 256, 256, 0, stream>>>(pos, idx_i, idx_j, edata, cnt, bucketj);

    const unsigned* fWh = (const unsigned*)(packs + P_FWH);

    for (int it = 0; it < 3; it++) {
        mlp1_k<<<313, 256, 0, stream>>>(
            q, packs + P_IC1 + it * 16384, ic1b + it * 128,
            packs + P_IC2 + it * 49152, ic2b + it * 384, x_bf);
        if (it == 0)
            gather_k<1><<<NA, 128, 0, stream>>>(
                fWh, fb, x_bf, mu_bf, edata, cnt, bucketj, it, q, muF);
        else
            gather_k<0><<<NA, 128, 0, stream>>>(
                fWh, fb, x_bf, mu_bf, edata, cnt, bucketj, it, q, muF);
        mixctx_k<<<(NA + 15) / 16, 256, 0, stream>>>(
            q, muF, mu_bf,
            packs + P_MIX + it * 32768,
            packs + P_C1 + it * 32768, c1b + it * 128,
            packs + P_C2 + it * 49152, c2b + it * 384);
    }

    readout_k<<<313, 256, 0, stream>>>(q, packs + P_O1, o1b, packs + P_O2, o2b,
                                       o3W, o3b, idx_m, y);
}